// Round 6
// baseline (90.129 us; speedup 1.0000x reference)
//
#include <hip/hip_runtime.h>
#include <hip/hip_bf16.h>

#define N_ 256
#define C_ 128
#define S_ 961
#define K_ 64
#define TS 32
#define NTILE 16
#define NTHREADS 512

typedef __attribute__((ext_vector_type(4))) float f32x4;
typedef __attribute__((ext_vector_type(8))) short bf16x8;
typedef __attribute__((ext_vector_type(4))) unsigned short us4;
typedef __attribute__((ext_vector_type(2))) unsigned short us2;

#define MFMA16(a, b, c) __builtin_amdgcn_mfma_f32_16x16x32_bf16((a), (b), (c), 0, 0, 0)

// truncation split: f = hi + lo with |err| <= 2^-16 |f|
static __device__ __forceinline__ void split_bf(float f, unsigned short& h, unsigned short& l) {
    unsigned int u = __builtin_bit_cast(unsigned int, f);
    unsigned int ur = u & 0xFFFF0000u;
    h = (unsigned short)(ur >> 16);
    float r = f - __builtin_bit_cast(float, ur);
    l = (unsigned short)(__builtin_bit_cast(unsigned int, r) >> 16);
}

template <int CTRL>
static __device__ __forceinline__ float dpp_add(float v) {
    int sw = __builtin_amdgcn_update_dpp(0, __builtin_bit_cast(int, v), CTRL, 0xF, 0xF, true);
    return v + __builtin_bit_cast(float, sw);
}
static __device__ __forceinline__ float wave_sum64(float v) {
    v = dpp_add<0xB1>(v);    // quad_perm xor1
    v = dpp_add<0x4E>(v);    // quad_perm xor2
    v = dpp_add<0x141>(v);   // row_half_mirror
    v = dpp_add<0x140>(v);   // row_mirror
    v += __shfl_xor(v, 16);
    v += __shfl_xor(v, 32);
    return v;
}

template <bool ATOMIC>
__global__ __launch_bounds__(NTHREADS, 4) void vlad_main(
    const float* __restrict__ x,       // [N,C,S]
    const float* __restrict__ conv_w,  // [K,C]
    const float* __restrict__ cent,    // [K,C]
    const float* __restrict__ aw,      // [C]
    const float* __restrict__ ab,      // [1]
    float* __restrict__ out,           // [N,K,C] (h=0 partial or atomic target)
    float* __restrict__ ws)            // [N,K,C] (h=1 partial)
{
    __shared__ unsigned short s_xs[2][C_][40];   // [hi/lo][c][s] pitch 80B
    __shared__ unsigned short s_xT[2][TS][136];  // [hi/lo][s][c] swizzled, pitch 272B
    __shared__ float s_d[K_][36];                // logits, pitch 144B
    __shared__ unsigned short s_u[2][K_][40];    // [hi/lo][k][s]
    __shared__ float s_ared[2][8][36];           // [ssq/hd][wave][s]
    __shared__ float s_wred[8][K_];
    __shared__ float s_wsum[K_];

    const int tid = threadIdx.x;
    const int bid = blockIdx.x;
    const int n = bid >> 1, h = bid & 1;
    const int sbase = h * 512;
    const int lane = tid & 63;
    const int w = tid >> 6;
    const int la = lane & 15;
    const int lg = lane >> 4;
    const float bias = ab[0];
    const float* xn = x + (size_t)n * (C_ * S_);

    // staging: 2c x 4s per thread
    const int c0 = (tid >> 3) * 2;
    const int s0l = (tid & 7) * 4;
    const float awr0 = aw[c0], awr1 = aw[c0 + 1];

    // GEMM1: wave w -> m-tile mt1, n-tile nt1
    const int mt1 = w >> 1, nt1 = w & 1;
    bf16x8 cwhi[4], cwlo[4];
    #pragma unroll
    for (int cc = 0; cc < 4; ++cc) {
        const float* p = conv_w + (la + 16 * mt1) * C_ + 8 * lg + 32 * cc;
        #pragma unroll
        for (int i = 0; i < 8; ++i) {
            unsigned short hh, ll;
            split_bf(p[i], hh, ll);
            cwhi[cc][i] = (short)hh;
            cwlo[cc][i] = (short)ll;
        }
    }

    // GEMM2: 2 m-tiles x 2 c-tiles per wave
    const int mtb2 = (w & 1) * 2;
    const int ctb2 = (w >> 1) * 2;
    f32x4 acc2[2][2];
    #pragma unroll
    for (int m = 0; m < 2; ++m)
        #pragma unroll
        for (int ci = 0; ci < 2; ++ci) acc2[m][ci] = (f32x4){0.f, 0.f, 0.f, 0.f};

    float wpart = 0.f;
    float pxA[2][4], pxB[2][4];

    // prefetch tile 0
    {
        int gs = sbase + s0l;
        #pragma unroll
        for (int r = 0; r < 2; ++r) {
            const float* pr = xn + (size_t)(c0 + r) * S_ + gs;
            #pragma unroll
            for (int j = 0; j < 4; ++j) pxA[r][j] = (gs + j < S_) ? pr[j] : 0.f;
        }
    }

#define TILE_BODY(T, PXC, PXN)                                                   \
{                                                                                \
    const int s0 = sbase + (T) * TS;                                             \
    /* prefetch next tile */                                                     \
    if ((T) + 1 < NTILE) {                                                       \
        int gs = s0 + TS + s0l;                                                  \
        _Pragma("unroll") for (int r = 0; r < 2; ++r) {                          \
            const float* pr = xn + (size_t)(c0 + r) * S_ + gs;                   \
            if (gs + 3 < S_) {                                                   \
                PXN[r][0]=pr[0]; PXN[r][1]=pr[1]; PXN[r][2]=pr[2]; PXN[r][3]=pr[3]; \
            } else {                                                             \
                _Pragma("unroll") for (int j = 0; j < 4; ++j)                    \
                    PXN[r][j] = (gs + j < S_) ? pr[j] : 0.f;                     \
            }                                                                    \
        }                                                                        \
    }                                                                            \
    /* stage xs, xT, alpha partials */                                           \
    {                                                                            \
        unsigned short hv[2][4], lv[2][4];                                       \
        float ssqp[4] = {0.f,0.f,0.f,0.f};                                       \
        float hdp[4]  = {0.f,0.f,0.f,0.f};                                       \
        _Pragma("unroll") for (int j = 0; j < 4; ++j) {                          \
            float f0 = PXC[0][j], f1 = PXC[1][j];                                \
            split_bf(f0, hv[0][j], lv[0][j]);                                    \
            split_bf(f1, hv[1][j], lv[1][j]);                                    \
            ssqp[j] = f0*f0 + f1*f1;                                             \
            hdp[j]  = fmaxf(f0, 0.f)*awr0 + fmaxf(f1, 0.f)*awr1;                 \
        }                                                                        \
        _Pragma("unroll") for (int r = 0; r < 2; ++r) {                          \
            us4 a = {hv[r][0],hv[r][1],hv[r][2],hv[r][3]};                       \
            us4 b = {lv[r][0],lv[r][1],lv[r][2],lv[r][3]};                       \
            *(us4*)&s_xs[0][c0+r][s0l] = a;                                      \
            *(us4*)&s_xs[1][c0+r][s0l] = b;                                      \
        }                                                                        \
        _Pragma("unroll") for (int j = 0; j < 4; ++j) {                          \
            int srow = s0l + j;                                                  \
            int cidx = c0 ^ (((srow >> 3) & 3) << 3);                            \
            us2 a = {hv[0][j], hv[1][j]};                                        \
            us2 b = {lv[0][j], lv[1][j]};                                        \
            *(us2*)&s_xT[0][srow][cidx] = a;                                     \
            *(us2*)&s_xT[1][srow][cidx] = b;                                     \
        }                                                                        \
        _Pragma("unroll") for (int j = 0; j < 4; ++j) {                          \
            ssqp[j] += __shfl_xor(ssqp[j], 8);                                   \
            ssqp[j] += __shfl_xor(ssqp[j], 16);                                  \
            ssqp[j] += __shfl_xor(ssqp[j], 32);                                  \
            hdp[j]  += __shfl_xor(hdp[j], 8);                                    \
            hdp[j]  += __shfl_xor(hdp[j], 16);                                   \
            hdp[j]  += __shfl_xor(hdp[j], 32);                                   \
        }                                                                        \
        if ((lane >> 3) == 0) {                                                  \
            f32x4 a = {ssqp[0],ssqp[1],ssqp[2],ssqp[3]};                         \
            f32x4 b = {hdp[0],hdp[1],hdp[2],hdp[3]};                             \
            *(f32x4*)&s_ared[0][w][s0l] = a;                                     \
            *(f32x4*)&s_ared[1][w][s0l] = b;                                     \
        }                                                                        \
    }                                                                            \
    __syncthreads();  /* A */                                                    \
    /* GEMM1 */                                                                  \
    {                                                                            \
        int srow = 16*nt1 + la;                                                  \
        int swz = ((srow >> 3) & 3) << 3;                                        \
        f32x4 d0 = {0.f,0.f,0.f,0.f};                                            \
        _Pragma("unroll") for (int cc = 0; cc < 4; ++cc) {                       \
            int cidx = (8*lg + 32*cc) ^ swz;                                     \
            bf16x8 bh = *(const bf16x8*)&s_xT[0][srow][cidx];                    \
            bf16x8 bl = *(const bf16x8*)&s_xT[1][srow][cidx];                    \
            d0 = MFMA16(cwlo[cc], bh, d0);                                       \
            d0 = MFMA16(cwhi[cc], bl, d0);                                       \
            d0 = MFMA16(cwhi[cc], bh, d0);                                       \
        }                                                                        \
        _Pragma("unroll") for (int i = 0; i < 4; ++i)                            \
            s_d[16*mt1 + 4*lg + i][16*nt1 + la] = d0[i];                         \
    }                                                                            \
    __syncthreads();  /* B */                                                    \
    /* softmax: wave w owns local cols 4w..4w+3, lane = k */                     \
    {                                                                            \
        int j4 = lane & 3, q8 = (lane >> 2) & 7;                                 \
        float ssq = s_ared[0][q8][4*w + j4];                                     \
        float hd  = s_ared[1][q8][4*w + j4];                                     \
        ssq += __shfl_xor(ssq, 4); ssq += __shfl_xor(ssq, 8); ssq += __shfl_xor(ssq, 16); \
        hd  += __shfl_xor(hd, 4);  hd  += __shfl_xor(hd, 8);  hd  += __shfl_xor(hd, 16);  \
        int sg = s0 + 4*w + j4;                                                  \
        float hm = (sg < S_) ? fmaxf(hd + bias, 0.f) : 0.f;                      \
        float al = hm / fmaxf(sqrtf(ssq), 1e-12f);                               \
        f32x4 dA = *(const f32x4*)&s_d[lane][4*w];                               \
        float uu[4];                                                             \
        _Pragma("unroll") for (int j = 0; j < 4; ++j) {                          \
            float alj = __shfl(al, j, 4);                                        \
            float hmj = __shfl(hm, j, 4);                                        \
            float dv = dA[j] * alj;                                              \
            float e = __expf(dv);                                                \
            float sm = wave_sum64(e);                                            \
            float wv = e * hmj * __builtin_amdgcn_rcpf(sm);                      \
            wpart += wv;                                                         \
            uu[j] = wv * alj;                                                    \
        }                                                                        \
        us4 h4, l4;                                                              \
        _Pragma("unroll") for (int j = 0; j < 4; ++j) {                          \
            unsigned short hh, ll;                                               \
            split_bf(uu[j], hh, ll);                                             \
            h4[j] = hh; l4[j] = ll;                                              \
        }                                                                        \
        *(us4*)&s_u[0][lane][4*w] = h4;                                          \
        *(us4*)&s_u[1][lane][4*w] = l4;                                          \
    }                                                                            \
    __syncthreads();  /* C */                                                    \
    /* GEMM2: K=32 (one step) */                                                 \
    {                                                                            \
        bf16x8 ah[2], al8[2];                                                    \
        _Pragma("unroll") for (int m = 0; m < 2; ++m) {                          \
            ah[m]  = *(const bf16x8*)&s_u[0][la + 16*(mtb2+m)][8*lg];            \
            al8[m] = *(const bf16x8*)&s_u[1][la + 16*(mtb2+m)][8*lg];            \
        }                                                                        \
        _Pragma("unroll") for (int ci = 0; ci < 2; ++ci) {                       \
            int c = la + 16*(ctb2+ci);                                           \
            bf16x8 bh2 = *(const bf16x8*)&s_xs[0][c][8*lg];                      \
            bf16x8 bl2 = *(const bf16x8*)&s_xs[1][c][8*lg];                      \
            _Pragma("unroll") for (int m = 0; m < 2; ++m) {                      \
                acc2[m][ci] = MFMA16(al8[m], bh2, acc2[m][ci]);                  \
                acc2[m][ci] = MFMA16(ah[m], bl2, acc2[m][ci]);                   \
                acc2[m][ci] = MFMA16(ah[m], bh2, acc2[m][ci]);                   \
            }                                                                    \
        }                                                                        \
    }                                                                            \
    __syncthreads();  /* D */                                                    \
}

    for (int t2 = 0; t2 < NTILE / 2; ++t2) {
        TILE_BODY(2 * t2,     pxA, pxB)
        TILE_BODY(2 * t2 + 1, pxB, pxA)
    }

    // ---- wsum reduce ----
    s_wred[w][lane] = wpart;
    __syncthreads();
    if (tid < K_) {
        float v = 0.f;
        #pragma unroll
        for (int q = 0; q < 8; ++q) v += s_wred[q][tid];
        s_wsum[tid] = v;
    }
    __syncthreads();

    // ---- write partial vlad (with centroid term folded) ----
    {
        float* dst = ATOMIC ? out : (h ? ws : out);
        #pragma unroll
        for (int m = 0; m < 2; ++m) {
            #pragma unroll
            for (int ci = 0; ci < 2; ++ci) {
                int c = la + 16 * (ctb2 + ci);
                #pragma unroll
                for (int i = 0; i < 4; ++i) {
                    int k = 16 * (mtb2 + m) + 4 * lg + i;
                    float val = acc2[m][ci][i] - cent[k * C_ + c] * s_wsum[k];
                    size_t off = (size_t)n * (K_ * C_) + k * C_ + c;
                    if (ATOMIC) atomicAdd(&dst[off], val);
                    else dst[off] = val;
                }
            }
        }
    }
}

template <bool WS>
__global__ __launch_bounds__(256) void vlad_norm(
    float* __restrict__ out, const float* __restrict__ ws)
{
    __shared__ float s_rs[K_], s_f[K_];
    __shared__ float s_fin;
    const int n = blockIdx.x, tid = threadIdx.x;
    const int k = tid >> 2, q = tid & 3;
    float* po = out + (size_t)n * (K_ * C_) + k * C_ + q * 32;
    const float* pw = ws + (size_t)n * (K_ * C_) + k * C_ + q * 32;

    float v[32];
    float ssq = 0.f;
    #pragma unroll
    for (int i = 0; i < 8; ++i) {
        f32x4 a = *(const f32x4*)&po[4 * i];
        if (WS) {
            f32x4 b = *(const f32x4*)&pw[4 * i];
            a[0]+=b[0]; a[1]+=b[1]; a[2]+=b[2]; a[3]+=b[3];
        }
        #pragma unroll
        for (int j = 0; j < 4; ++j) { v[4*i+j] = a[j]; ssq += a[j]*a[j]; }
    }
    ssq += __shfl_xor(ssq, 1);
    ssq += __shfl_xor(ssq, 2);
    if (q == 0) {
        float rs = 1.0f / fmaxf(sqrtf(ssq), 1e-12f);
        s_rs[k] = rs;
        s_f[k] = ssq * rs * rs;
    }
    __syncthreads();
    if (tid < 64) {
        float f = s_f[tid];
        #pragma unroll
        for (int m = 1; m < 64; m <<= 1) f += __shfl_xor(f, m);
        if (tid == 0) {
            float n1 = sqrtf(f);
            float sc1 = 1.0f / fmaxf(n1, 1e-12f);
            float n2 = n1 * sc1;
            float sc2 = 1.0f / fmaxf(n2, 1e-12f);
            s_fin = sc1 * sc2;
        }
    }
    __syncthreads();
    float sc = s_rs[k] * s_fin;
    #pragma unroll
    for (int i = 0; i < 8; ++i) {
        f32x4 a = {v[4*i]*sc, v[4*i+1]*sc, v[4*i+2]*sc, v[4*i+3]*sc};
        *(f32x4*)&po[4 * i] = a;
    }
}

extern "C" void kernel_launch(void* const* d_in, const int* in_sizes, int n_in,
                              void* d_out, int out_size, void* d_ws, size_t ws_size,
                              hipStream_t stream) {
    const float* x      = (const float*)d_in[0];
    const float* conv_w = (const float*)d_in[1];
    const float* cent   = (const float*)d_in[2];
    const float* aw     = (const float*)d_in[3];
    const float* ab     = (const float*)d_in[4];
    float* outp = (float*)d_out;
    float* wsp  = (float*)d_ws;

    const size_t need = (size_t)N_ * K_ * C_ * sizeof(float);
    if (ws_size >= need) {
        vlad_main<false><<<2 * N_, NTHREADS, 0, stream>>>(x, conv_w, cent, aw, ab, outp, wsp);
        vlad_norm<true><<<N_, 256, 0, stream>>>(outp, wsp);
    } else {
        hipMemsetAsync(d_out, 0, need, stream);
        vlad_main<true><<<2 * N_, NTHREADS, 0, stream>>>(x, conv_w, cent, aw, ab, outp, wsp);
        vlad_norm<false><<<N_, 256, 0, stream>>>(outp, nullptr);
    }
}

// Round 7
// 61.387 us; speedup vs baseline: 1.4682x; 1.4682x over previous
//
#include <hip/hip_runtime.h>
#include <hip/hip_bf16.h>

#define N_ 256
#define C_ 128
#define S_ 961
#define K_ 64
#define TS 64
#define NTILE 16
#define NTHREADS 512

typedef __attribute__((ext_vector_type(4))) float f32x4;
typedef __attribute__((ext_vector_type(8))) _Float16 f16x8;
typedef __attribute__((ext_vector_type(4))) _Float16 f16x4;

#define MFMAF(a, b, c) __builtin_amdgcn_mfma_f32_16x16x32_f16((a), (b), (c), 0, 0, 0)

template <int CTRL>
static __device__ __forceinline__ float dpp_add(float v) {
    int sw = __builtin_amdgcn_update_dpp(0, __builtin_bit_cast(int, v), CTRL, 0xF, 0xF, true);
    return v + __builtin_bit_cast(float, sw);
}
// sum over all 64 lanes, broadcast (4 VALU-DPP + 2 shfl)
static __device__ __forceinline__ float wave_sum64(float v) {
    v = dpp_add<0xB1>(v);    // quad_perm xor1
    v = dpp_add<0x4E>(v);    // quad_perm xor2
    v = dpp_add<0x141>(v);   // row_half_mirror
    v = dpp_add<0x140>(v);   // row_mirror
    v += __shfl_xor(v, 16);
    v += __shfl_xor(v, 32);
    return v;
}

__global__ __launch_bounds__(NTHREADS, 1) void vlad_mfma_kernel(
    const float* __restrict__ x,       // [N,C,S]
    const float* __restrict__ conv_w,  // [K,C]
    const float* __restrict__ cent,    // [K,C]
    const float* __restrict__ aw,      // [C]
    const float* __restrict__ ab,      // [1]
    float* __restrict__ out)           // [N, K*C]
{
    __shared__ union {
        _Float16 xs[2][C_][72];        // [buf][c][s] pitch 144B, fp16 single-plane
        float vl[K_][130];
    } sxv;
    __shared__ _Float16 s_xT[TS][136]; // [s][c] swizzled, pitch 272B
    __shared__ float s_d[K_][68];      // logits fp32, pitch 272B
    __shared__ _Float16 s_u[K_][72];   // u fp16
    __shared__ float s_ared[2][8][68]; // [ssq/hd][wave][s]; [0] reused as wred
    __shared__ float s_wsum[K_], s_rs[K_];
    __shared__ float s_fin;

    const int tid = threadIdx.x;
    const int n = blockIdx.x;
    const int lane = tid & 63;
    const int w = tid >> 6;          // wave 0..7
    const int la = lane & 15;
    const int lg = lane >> 4;
    const float bias = ab[0];
    const float* xn = x + (size_t)n * (C_ * S_);

    // staging: 4c x 4s per thread
    const int cb = tid >> 4;
    const int c0 = cb * 4;
    const int s0l = (tid & 15) * 4;

    float awr[4];
    #pragma unroll
    for (int r = 0; r < 4; ++r) awr[r] = aw[c0 + r];

    // GEMM1: wave w -> n-tile nt1 (0..3), m-tiles {mtb, mtb+1}
    const int nt1 = w & 3;
    const int mtb = (w >> 2) * 2;
    f16x8 cw[2][4];
    #pragma unroll
    for (int m2 = 0; m2 < 2; ++m2) {
        const float* p = conv_w + (la + 16 * (mtb + m2)) * C_ + 8 * lg;
        #pragma unroll
        for (int cc = 0; cc < 4; ++cc)
            #pragma unroll
            for (int i = 0; i < 8; ++i)
                cw[m2][cc][i] = (_Float16)p[32 * cc + i];
    }

    // GEMM2: 2 m-tiles x 2 c-tiles per wave
    const int mtb2 = (w & 1) * 2;
    const int ctb2 = (w >> 1) * 2;
    f32x4 acc2[2][2];
    #pragma unroll
    for (int m = 0; m < 2; ++m)
        #pragma unroll
        for (int ci = 0; ci < 2; ++ci) acc2[m][ci] = (f32x4){0.f, 0.f, 0.f, 0.f};

    float wpart = 0.f;
    float pxA[4][4], pxB[4][4];

    // prefetch tile 0 (s0l+3 <= 63 < S_)
    #pragma unroll
    for (int r = 0; r < 4; ++r) {
        const float* pr = xn + (size_t)(c0 + r) * S_ + s0l;
        pxA[r][0] = pr[0]; pxA[r][1] = pr[1]; pxA[r][2] = pr[2]; pxA[r][3] = pr[3];
    }

#define GEMM2_STEP(SB)                                                          \
    {                                                                           \
        _Pragma("unroll") for (int sc = 0; sc < 2; ++sc) {                      \
            f16x8 ua[2];                                                        \
            _Pragma("unroll") for (int m = 0; m < 2; ++m)                       \
                ua[m] = *(const f16x8*)&s_u[la + 16*(mtb2+m)][8*lg + 32*sc];    \
            _Pragma("unroll") for (int ci = 0; ci < 2; ++ci) {                  \
                f16x8 xb = *(const f16x8*)&sxv.xs[SB][la + 16*(ctb2+ci)][8*lg + 32*sc]; \
                _Pragma("unroll") for (int m = 0; m < 2; ++m)                   \
                    acc2[m][ci] = MFMAF(ua[m], xb, acc2[m][ci]);                \
            }                                                                   \
        }                                                                       \
    }

#define TILE_BODY(T, PXC, PXN, BUF)                                             \
{                                                                               \
    /* prefetch px(T+1) */                                                      \
    if ((T) + 1 < NTILE) {                                                      \
        int gs = ((T)+1)*TS + s0l;                                              \
        _Pragma("unroll") for (int r = 0; r < 4; ++r) {                         \
            const float* pr = xn + (size_t)(c0+r)*S_ + gs;                      \
            if (gs + 3 < S_) {                                                  \
                PXN[r][0]=pr[0]; PXN[r][1]=pr[1]; PXN[r][2]=pr[2]; PXN[r][3]=pr[3]; \
            } else {                                                            \
                _Pragma("unroll") for (int j = 0; j < 4; ++j)                   \
                    PXN[r][j] = (gs + j < S_) ? pr[j] : 0.f;                    \
            }                                                                   \
        }                                                                       \
    }                                                                           \
    /* GEMM2(T-1) from the other xs buffer (registers+LDS reads only) */        \
    if ((T) > 0) GEMM2_STEP((BUF)^1)                                            \
    /* stage xs[BUF], xT, ared */                                               \
    {                                                                           \
        float ssqp[4], hdp[4];                                                  \
        _Pragma("unroll") for (int j = 0; j < 4; ++j) { ssqp[j]=0.f; hdp[j]=0.f; } \
        _Pragma("unroll") for (int r = 0; r < 4; ++r) {                         \
            f16x4 v;                                                            \
            _Pragma("unroll") for (int j = 0; j < 4; ++j) {                     \
                float f = PXC[r][j];                                            \
                v[j] = (_Float16)f;                                             \
                ssqp[j] += f*f;                                                 \
                hdp[j]  += fmaxf(f, 0.f)*awr[r];                                \
            }                                                                   \
            *(f16x4*)&sxv.xs[BUF][c0+r][s0l] = v;                               \
        }                                                                       \
        _Pragma("unroll") for (int j = 0; j < 4; ++j) {                         \
            int srow = s0l + j;                                                 \
            int cidx = c0 ^ (((srow >> 3) & 3) << 3);                           \
            f16x4 vT = {(_Float16)PXC[0][j], (_Float16)PXC[1][j],               \
                        (_Float16)PXC[2][j], (_Float16)PXC[3][j]};              \
            *(f16x4*)&s_xT[srow][cidx] = vT;                                    \
        }                                                                       \
        _Pragma("unroll") for (int j = 0; j < 4; ++j) {                         \
            ssqp[j] += __shfl_xor(ssqp[j], 16);                                 \
            ssqp[j] += __shfl_xor(ssqp[j], 32);                                 \
            hdp[j]  += __shfl_xor(hdp[j], 16);                                  \
            hdp[j]  += __shfl_xor(hdp[j], 32);                                  \
        }                                                                       \
        if (lg == 0) {                                                          \
            f32x4 a = {ssqp[0],ssqp[1],ssqp[2],ssqp[3]};                        \
            f32x4 b = {hdp[0],hdp[1],hdp[2],hdp[3]};                            \
            *(f32x4*)&s_ared[0][w][s0l] = a;                                    \
            *(f32x4*)&s_ared[1][w][s0l] = b;                                    \
        }                                                                       \
    }                                                                           \
    __syncthreads();  /* A */                                                   \
    /* GEMM1(T): 8 MFMA per wave */                                             \
    {                                                                           \
        int srow = 16*nt1 + la;                                                 \
        int swz = ((srow >> 3) & 3) << 3;                                       \
        f32x4 d0 = {0.f,0.f,0.f,0.f}, d1 = {0.f,0.f,0.f,0.f};                   \
        _Pragma("unroll") for (int cc = 0; cc < 4; ++cc) {                      \
            f16x8 b = *(const f16x8*)&s_xT[srow][(8*lg + 32*cc) ^ swz];         \
            d0 = MFMAF(cw[0][cc], b, d0);                                       \
            d1 = MFMAF(cw[1][cc], b, d1);                                       \
        }                                                                       \
        _Pragma("unroll") for (int i = 0; i < 4; ++i) {                         \
            s_d[16*mtb + 4*lg + i][16*nt1 + la]     = d0[i];                    \
            s_d[16*(mtb+1) + 4*lg + i][16*nt1 + la] = d1[i];                    \
        }                                                                       \
    }                                                                           \
    __syncthreads();  /* B */                                                   \
    /* softmax: wave w owns cols 8w..8w+7, lane = k; alpha via shuffles */      \
    {                                                                           \
        int j8 = lane & 7, q8 = lane >> 3;                                      \
        float ssq = s_ared[0][q8][8*w + j8];                                    \
        float hd  = s_ared[1][q8][8*w + j8];                                    \
        ssq += __shfl_xor(ssq, 8); ssq += __shfl_xor(ssq, 16); ssq += __shfl_xor(ssq, 32); \
        hd  += __shfl_xor(hd, 8);  hd  += __shfl_xor(hd, 16);  hd  += __shfl_xor(hd, 32);  \
        int sg = (T)*TS + 8*w + j8;                                             \
        float hm = (sg < S_) ? fmaxf(hd + bias, 0.f) : 0.f;                     \
        float al = hm / fmaxf(sqrtf(ssq), 1e-12f);                              \
        const float* drow = &s_d[lane][8*w];                                    \
        f32x4 dA = *(const f32x4*)drow;                                         \
        f32x4 dB = *(const f32x4*)(drow + 4);                                   \
        f16x8 u8;                                                               \
        _Pragma("unroll") for (int j = 0; j < 8; ++j) {                         \
            float alj = __shfl(al, j, 8);                                       \
            float hmj = __shfl(hm, j, 8);                                       \
            float dv = ((j < 4) ? dA[j] : dB[j-4]) * alj;                       \
            float e = __expf(dv);                                               \
            float sm = wave_sum64(e);                                           \
            float wv = e * hmj * __builtin_amdgcn_rcpf(sm);                     \
            wpart += wv;                                                        \
            u8[j] = (_Float16)(wv * alj);                                       \
        }                                                                       \
        *(f16x8*)&s_u[lane][8*w] = u8;                                          \
    }                                                                           \
    __syncthreads();  /* C */                                                   \
}

    for (int tp = 0; tp < NTILE; tp += 2) {
        TILE_BODY(tp,     pxA, pxB, 0)
        TILE_BODY(tp + 1, pxB, pxA, 1)
    }
    // final GEMM2(15): xs buffer 1
    GEMM2_STEP(1)

    // ================= epilogue =================
    s_ared[0][w][lane] = wpart;     // reuse as wred
    __syncthreads();
    if (tid < K_) {
        float v = 0.f;
        #pragma unroll
        for (int q = 0; q < 8; ++q) v += s_ared[0][q][tid];
        s_wsum[tid] = v;
    }
    __syncthreads();

    {
        #pragma unroll
        for (int m = 0; m < 2; ++m) {
            #pragma unroll
            for (int ci = 0; ci < 2; ++ci) {
                int c = la + 16 * (ctb2 + ci);
                #pragma unroll
                for (int i = 0; i < 4; ++i) {
                    int k = 16 * (mtb2 + m) + 4 * lg + i;
                    sxv.vl[k][c] = acc2[m][ci][i] - cent[k * C_ + c] * s_wsum[k];
                }
            }
        }
    }
    __syncthreads();

    // per-cluster row norm over c
    {
        int k = tid >> 3;
        int q = tid & 7;
        float ssq = 0.f;
        #pragma unroll
        for (int i = 0; i < 16; ++i) {
            float v = sxv.vl[k][q * 16 + i];
            ssq += v * v;
        }
        #pragma unroll
        for (int m = 1; m < 8; m <<= 1) ssq += __shfl_xor(ssq, m);
        if (q == 0) {
            float rs = 1.0f / fmaxf(sqrtf(ssq), 1e-12f);
            s_rs[k] = rs;
            s_ared[1][0][k] = ssq * rs * rs;
        }
    }
    __syncthreads();

    if (tid < 64) {
        float v = s_ared[1][0][tid];
        #pragma unroll
        for (int m = 1; m < 64; m <<= 1) v += __shfl_xor(v, m);
        if (tid == 0) {
            float n1 = sqrtf(v);
            float sc1 = 1.0f / fmaxf(n1, 1e-12f);
            float n2 = n1 * sc1;
            float sc2 = 1.0f / fmaxf(n2, 1e-12f);
            s_fin = sc1 * sc2;
        }
    }
    __syncthreads();

    {
        float fs = s_fin;
        float* on = out + (size_t)n * (K_ * C_);
        #pragma unroll
        for (int it = 0; it < 16; ++it) {
            int idx = tid + it * NTHREADS;
            int k = idx >> 7, c = idx & 127;
            on[idx] = sxv.vl[k][c] * s_rs[k] * fs;
        }
    }
}

extern "C" void kernel_launch(void* const* d_in, const int* in_sizes, int n_in,
                              void* d_out, int out_size, void* d_ws, size_t ws_size,
                              hipStream_t stream) {
    const float* x      = (const float*)d_in[0];
    const float* conv_w = (const float*)d_in[1];
    const float* cent   = (const float*)d_in[2];
    const float* aw     = (const float*)d_in[3];
    const float* ab     = (const float*)d_in[4];
    float* outp = (float*)d_out;

    vlad_mfma_kernel<<<N_, NTHREADS, 0, stream>>>(x, conv_w, cent, aw, ab, outp);
}